// Round 4
// baseline (964.987 us; speedup 1.0000x reference)
//
#include <hip/hip_runtime.h>

// ---- hash / bucket constants ----
#define HBITS 19
#define HSIZE (1u << HBITS)
#define HMASK (HSIZE - 1u)
#define EMPTY_KEY 0xFFFFFFFFu
#define SLOTS 8   // direct slots per voxel; overflow (P~1e-4) goes to chain

__device__ __forceinline__ unsigned hash_key(unsigned k) {
    return (k * 2654435761u) >> (32 - HBITS);
}

__device__ __forceinline__ unsigned pack_key(int4 c) {
    // c.x = batch (<4), c.y/z/w = xyz in [0,256)
    return ((unsigned)c.x << 24) | ((unsigned)c.y << 16) |
           ((unsigned)c.z << 8) | (unsigned)c.w;
}

// Kernel A: insert voxel keys; htab[h] = (key, min original index).
__global__ __launch_bounds__(256)
void build_hash(const int4* __restrict__ tgt_coords, int M,
                uint2* __restrict__ htab) {
    int v = blockIdx.x * blockDim.x + threadIdx.x;
    if (v >= M) return;
    unsigned key = pack_key(tgt_coords[v]);
    unsigned h = hash_key(key);
    while (true) {
        unsigned prev = atomicCAS(&htab[h].x, EMPTY_KEY, key);
        if (prev == EMPTY_KEY || prev == key) {
            atomicMin(&htab[h].y, (unsigned)v);   // canonical = min index
            break;
        }
        h = (h + 1u) & HMASK;
    }
}

// Kernel B: each point probes the hash for its canonical voxel and claims a
// bucket slot. cnt[] init = -1 (0xFF memset) so atomicAdd+1 gives slot 0,1,...
__global__ __launch_bounds__(256)
void fill_slots(const int* __restrict__ pts_idx,
                const int4* __restrict__ tgt_coords,
                const uint2* __restrict__ htab,
                int BN,
                int* __restrict__ cnt,      // (M) init -1
                int* __restrict__ slotbuf,  // (M*SLOTS) no init needed
                int* __restrict__ ohead,    // (M) init -1
                int* __restrict__ nxt) {    // (BN) no init needed
    int p = blockIdx.x * blockDim.x + threadIdx.x;
    if (p >= BN) return;
    int vox = pts_idx[p];
    unsigned key = pack_key(tgt_coords[vox]);
    unsigned h = hash_key(key);
    uint2 e = htab[h];
    while (e.x != key) { h = (h + 1u) & HMASK; e = htab[h]; }
    int c = (int)e.y;
    int idx = atomicAdd(&cnt[c], 1) + 1;
    if (idx < SLOTS) slotbuf[c * SLOTS + idx] = p;
    else             nxt[p] = atomicExch(&ohead[c], p);   // rare
}

// Kernel C: 64 voxels/block, 8 per group-of-32. Phase 1: gather-mean into
// xbuf (LDS). Phase 2: register-blocked matmul — lane owns oc=g and 8 voxel
// accumulators; W read from LDS transposed (Wt[oc][k], pad 98 -> 2-way only)
// as float2 shared across 16 voxels/wave. x read as b128 broadcast.
#define VGRP 8
#define XPAD 100   // xbuf row stride in floats (16B-aligned, bank-friendly)
#define WPAD 98    // Wt row stride in floats (8B-aligned, 2-way only)
__global__ __launch_bounds__(256)
void fuse_reg(const float2* __restrict__ pf2,   // (BN,64) as (BN,32) float2
              const int* __restrict__ cnt,
              const int4* __restrict__ slot4,   // slotbuf as (M,2) int4
              const int* __restrict__ ohead,
              const int* __restrict__ nxt,
              const float* __restrict__ tgt_feats,
              const float* __restrict__ W,
              const float* __restrict__ bias,
              int M,
              float* __restrict__ out) {
    __shared__ __align__(16) float xbuf[64 * XPAD];   // 25.6 KB
    __shared__ __align__(16) float Wt[32 * WPAD];     // 12.5 KB

    int t = threadIdx.x;
    // stage W transposed: Wt[oc][k] = W[k*32+oc]; coalesced global read,
    // write banks (2*oc+k)%32 across lanes -> 2-way, free.
    for (int i = t; i < 96 * 32; i += 256) {
        int k = i >> 5, oc = i & 31;
        Wt[oc * WPAD + k] = W[i];
    }

    int grp = t >> 5;
    int g   = t & 31;           // oc for phase 2, channel-pair for phase 1
    int vbase = blockIdx.x * 64 + grp * VGRP;
    float bval = bias[g];

    // ---- phase 1: gather-mean for this group's 8 voxels ----
#pragma unroll
    for (int vv = 0; vv < VGRP; ++vv) {
        int v = vbase + vv;
        if (v >= M) break;
        int n = cnt[v] + 1;
        int4 sa = make_int4(0, 0, 0, 0), sb = make_int4(0, 0, 0, 0);
        if (n > 0) sa = slot4[(size_t)v * 2];
        if (n > 4) sb = slot4[(size_t)v * 2 + 1];
        float2 f0 = {0,0}, f1 = {0,0}, f2 = {0,0}, f3 = {0,0};
        float2 f4 = {0,0}, f5 = {0,0}, f6 = {0,0}, f7 = {0,0};
        if (n > 0) f0 = pf2[(size_t)sa.x * 32 + g];
        if (n > 1) f1 = pf2[(size_t)sa.y * 32 + g];
        if (n > 2) f2 = pf2[(size_t)sa.z * 32 + g];
        if (n > 3) f3 = pf2[(size_t)sa.w * 32 + g];
        if (n > 4) f4 = pf2[(size_t)sb.x * 32 + g];
        if (n > 5) f5 = pf2[(size_t)sb.y * 32 + g];
        if (n > 6) f6 = pf2[(size_t)sb.z * 32 + g];
        if (n > 7) f7 = pf2[(size_t)sb.w * 32 + g];
        float sx = ((f0.x + f1.x) + (f2.x + f3.x)) + ((f4.x + f5.x) + (f6.x + f7.x));
        float sy = ((f0.y + f1.y) + (f2.y + f3.y)) + ((f4.y + f5.y) + (f6.y + f7.y));
        if (n > SLOTS) {   // extremely rare overflow chain
            int p = ohead[v];
            while (p >= 0) {
                float2 f = pf2[(size_t)p * 32 + g];
                sx += f.x; sy += f.y;
                p = nxt[p];
            }
        }
        float inv = 1.0f / fmaxf((float)n, 1.0f);
        int row = (grp * VGRP + vv) * XPAD;
        *(float2*)&xbuf[row + 32 + 2 * g] = make_float2(sx * inv, sy * inv);
        if (g < 16) {
            float2 tf = ((const float2*)tgt_feats)[(size_t)v * 16 + g];
            *(float2*)&xbuf[row + 2 * g] = tf;
        }
    }
    __syncthreads();

    // ---- phase 2: lane g computes out[vbase+vv][g] for vv=0..7 ----
    float acc[VGRP];
#pragma unroll
    for (int vv = 0; vv < VGRP; ++vv) acc[vv] = bval;

#pragma unroll
    for (int k4 = 0; k4 < 24; ++k4) {
        float2 w01 = *(const float2*)&Wt[g * WPAD + k4 * 4];
        float2 w23 = *(const float2*)&Wt[g * WPAD + k4 * 4 + 2];
#pragma unroll
        for (int vv = 0; vv < VGRP; ++vv) {
            float4 x = *(const float4*)&xbuf[(grp * VGRP + vv) * XPAD + k4 * 4];
            acc[vv] = fmaf(x.x, w01.x, acc[vv]);
            acc[vv] = fmaf(x.y, w01.y, acc[vv]);
            acc[vv] = fmaf(x.z, w23.x, acc[vv]);
            acc[vv] = fmaf(x.w, w23.y, acc[vv]);
        }
    }
#pragma unroll
    for (int vv = 0; vv < VGRP; ++vv) {
        int v = vbase + vv;
        if (v < M) out[(size_t)v * 32 + g] = acc[vv];
    }
}

extern "C" void kernel_launch(void* const* d_in, const int* in_sizes, int n_in,
                              void* d_out, int out_size, void* d_ws, size_t ws_size,
                              hipStream_t stream) {
    const float* pfeat      = (const float*)d_in[0];  // (BN,64)
    const float* tgt_feats  = (const float*)d_in[1];  // (M,32)
    const float* W_fuse     = (const float*)d_in[2];  // (96,32)
    const float* b_fuse     = (const float*)d_in[3];  // (32,)
    const int*   tgt_coords = (const int*)d_in[4];    // (M,4)
    const int*   pts_idx    = (const int*)d_in[5];    // (BN,)
    float* out = (float*)d_out;                       // (M,32)

    const int M  = in_sizes[4] / 4;
    const int BN = in_sizes[5];

    // workspace: [htab 4MB | cnt M | ohead M]  <- single 0xFF memset region
    //            [slotbuf M*8 | nxt BN]        <- write-before-read, no init
    char* ws = (char*)d_ws;
    uint2* htab    = (uint2*)ws;
    int*   cnt     = (int*)(ws + (size_t)HSIZE * 8);
    int*   ohead   = (int*)(ws + (size_t)HSIZE * 8 + (size_t)M * 4);
    int*   slotbuf = (int*)(ws + (size_t)HSIZE * 8 + (size_t)M * 8);
    int*   nxt     = (int*)(ws + (size_t)HSIZE * 8 + (size_t)M * 8 + (size_t)M * SLOTS * 4);

    size_t ff_bytes = (size_t)HSIZE * 8 + (size_t)M * 8;
    hipMemsetAsync(htab, 0xFF, ff_bytes, stream);  // EMPTY_KEY / UINT_MAX / -1 / -1

    const int TB = 256;
    build_hash<<<(M + TB - 1) / TB, TB, 0, stream>>>(
        (const int4*)tgt_coords, M, htab);
    fill_slots<<<(BN + TB - 1) / TB, TB, 0, stream>>>(
        pts_idx, (const int4*)tgt_coords, htab, BN, cnt, slotbuf, ohead, nxt);
    fuse_reg<<<(M + 63) / 64, TB, 0, stream>>>(
        (const float2*)pfeat, cnt, (const int4*)slotbuf, ohead, nxt,
        tgt_feats, W_fuse, b_fuse, M, out);
}

// Round 5
// 319.911 us; speedup vs baseline: 3.0164x; 3.0164x over previous
//
#include <hip/hip_runtime.h>

// ---- hash / bucket constants ----
#define HBITS 19
#define HSIZE (1u << HBITS)
#define HMASK (HSIZE - 1u)
#define EMPTY_KEY 0xFFFFFFFFu
#define SLOTS 8   // direct slots per voxel; overflow (P~1e-4) goes to chain

__device__ __forceinline__ unsigned hash_key(unsigned k) {
    return (k * 2654435761u) >> (32 - HBITS);
}

__device__ __forceinline__ unsigned pack_key(int4 c) {
    // c.x = batch (<4), c.y/z/w = xyz in [0,256)
    return ((unsigned)c.x << 24) | ((unsigned)c.y << 16) |
           ((unsigned)c.z << 8) | (unsigned)c.w;
}

// Kernel A: insert voxel keys; htab[h] = (key, min original index).
__global__ __launch_bounds__(256)
void build_hash(const int4* __restrict__ tgt_coords, int M,
                uint2* __restrict__ htab) {
    int v = blockIdx.x * blockDim.x + threadIdx.x;
    if (v >= M) return;
    unsigned key = pack_key(tgt_coords[v]);
    unsigned h = hash_key(key);
    while (true) {
        unsigned prev = atomicCAS(&htab[h].x, EMPTY_KEY, key);
        if (prev == EMPTY_KEY || prev == key) {
            atomicMin(&htab[h].y, (unsigned)v);   // canonical = min index
            break;
        }
        h = (h + 1u) & HMASK;
    }
}

// Kernel B: each point probes the hash for its canonical voxel and claims a
// bucket slot. cnt[] init = -1 (0xFF memset) so atomicAdd+1 gives slot 0,1,...
__global__ __launch_bounds__(256)
void fill_slots(const int* __restrict__ pts_idx,
                const int4* __restrict__ tgt_coords,
                const uint2* __restrict__ htab,
                int BN,
                int* __restrict__ cnt,      // (M) init -1
                int* __restrict__ slotbuf,  // (M*SLOTS) no init needed
                int* __restrict__ ohead,    // (M) init -1
                int* __restrict__ nxt) {    // (BN) no init needed
    int p = blockIdx.x * blockDim.x + threadIdx.x;
    if (p >= BN) return;
    int vox = pts_idx[p];
    unsigned key = pack_key(tgt_coords[vox]);
    unsigned h = hash_key(key);
    uint2 e = htab[h];
    while (e.x != key) { h = (h + 1u) & HMASK; e = htab[h]; }
    int c = (int)e.y;
    int idx = atomicAdd(&cnt[c], 1) + 1;
    if (idx < SLOTS) slotbuf[c * SLOTS + idx] = p;
    else             nxt[p] = atomicExch(&ohead[c], p);   // rare
}

// Kernel C: ONE WAVE64 PER VOXEL, k split across half-waves.
// Lane l: oc = l&31, khalf = l>>5. W half-column (48 floats) lives in VGPRs,
// loaded once per block (amortized over ~50 voxels/wave). Gather: lane l owns
// img channel l (64 lanes x 4B = coalesced 256B row reads). x (96 floats)
// round-trips through a WAVE-PRIVATE LDS row -> no __syncthreads at all.
// Phase 2: 12 broadcast ds_read_b128 per voxel + 48 FMA, combine halves with
// one shfl_xor(32). LDS cyc/vox ~144 vs round-3's 423.
__global__ __launch_bounds__(256)
void fuse_wave(const float* __restrict__ pf,     // (BN,64)
               const int* __restrict__ cnt,
               const int4* __restrict__ slot4,   // slotbuf as (M,2) int4
               const int* __restrict__ ohead,
               const int* __restrict__ nxt,
               const float* __restrict__ tgt_feats,
               const float* __restrict__ W,
               const float* __restrict__ bias,
               int M,
               float* __restrict__ out) {
    __shared__ __align__(16) float xbuf[4][96];   // one 384B row per wave

    int t = threadIdx.x;
    int wid = t >> 6;        // wave within block
    int l   = t & 63;
    int oc  = l & 31;
    int kh  = l >> 5;        // 0: k=0..47, 1: k=48..95

    // W half-column into registers: wreg[j] = W[(kh*48+j)*32 + oc]
    float wreg[48];
#pragma unroll
    for (int j = 0; j < 48; ++j) wreg[j] = W[(kh * 48 + j) * 32 + oc];
    float bval = bias[oc];

    float* xrow = &xbuf[wid][0];
    const float4* xr4 = (const float4*)(xrow + kh * 48);

    int gwave  = blockIdx.x * 4 + wid;
    int nwaves = gridDim.x * 4;

#pragma unroll 1
    for (int v = gwave; v < M; v += nwaves) {
        // ---- gather-mean: lane l accumulates img channel l ----
        int n = cnt[v] + 1;
        int4 sa = make_int4(0, 0, 0, 0), sb = make_int4(0, 0, 0, 0);
        if (n > 0) sa = slot4[(size_t)v * 2];
        if (n > 4) sb = slot4[(size_t)v * 2 + 1];
        float f0 = 0.f, f1 = 0.f, f2 = 0.f, f3 = 0.f;
        float f4 = 0.f, f5 = 0.f, f6 = 0.f, f7 = 0.f;
        if (n > 0) f0 = pf[(size_t)sa.x * 64 + l];
        if (n > 1) f1 = pf[(size_t)sa.y * 64 + l];
        if (n > 2) f2 = pf[(size_t)sa.z * 64 + l];
        if (n > 3) f3 = pf[(size_t)sa.w * 64 + l];
        if (n > 4) f4 = pf[(size_t)sb.x * 64 + l];
        if (n > 5) f5 = pf[(size_t)sb.y * 64 + l];
        if (n > 6) f6 = pf[(size_t)sb.z * 64 + l];
        if (n > 7) f7 = pf[(size_t)sb.w * 64 + l];
        float s = ((f0 + f1) + (f2 + f3)) + ((f4 + f5) + (f6 + f7));
        if (n > SLOTS) {   // extremely rare overflow chain
            int p = ohead[v];
            while (p >= 0) {
                s += pf[(size_t)p * 64 + l];
                p = nxt[p];
            }
        }
        float inv = 1.0f / fmaxf((float)n, 1.0f);

        // ---- stage x = [tgt(32) | mean(64)] in wave-private LDS row ----
        xrow[32 + l] = s * inv;                       // 64 lanes, 2-way banks: free
        if (l < 32) xrow[l] = tgt_feats[(size_t)v * 32 + l];
        // wave-synchronous: ds writes complete before dependent ds reads
        // (same wave, compiler-inserted lgkmcnt) — no barrier needed.

        // ---- half-column dot: acc = sum_k x[kh*48+k] * W[.][oc] ----
        float acc = 0.0f;
#pragma unroll
        for (int k4 = 0; k4 < 12; ++k4) {
            float4 x = xr4[k4];                       // broadcast per half-wave
            acc = fmaf(x.x, wreg[k4 * 4 + 0], acc);
            acc = fmaf(x.y, wreg[k4 * 4 + 1], acc);
            acc = fmaf(x.z, wreg[k4 * 4 + 2], acc);
            acc = fmaf(x.w, wreg[k4 * 4 + 3], acc);
        }
        acc += __shfl_xor(acc, 32, 64);               // combine k-halves
        if (l < 32) out[(size_t)v * 32 + oc] = acc + bval;
    }
}

extern "C" void kernel_launch(void* const* d_in, const int* in_sizes, int n_in,
                              void* d_out, int out_size, void* d_ws, size_t ws_size,
                              hipStream_t stream) {
    const float* pfeat      = (const float*)d_in[0];  // (BN,64)
    const float* tgt_feats  = (const float*)d_in[1];  // (M,32)
    const float* W_fuse     = (const float*)d_in[2];  // (96,32)
    const float* b_fuse     = (const float*)d_in[3];  // (32,)
    const int*   tgt_coords = (const int*)d_in[4];    // (M,4)
    const int*   pts_idx    = (const int*)d_in[5];    // (BN,)
    float* out = (float*)d_out;                       // (M,32)

    const int M  = in_sizes[4] / 4;
    const int BN = in_sizes[5];

    // workspace: [htab 4MB | cnt M | ohead M]  <- single 0xFF memset region
    //            [slotbuf M*8 | nxt BN]        <- write-before-read, no init
    char* ws = (char*)d_ws;
    uint2* htab    = (uint2*)ws;
    int*   cnt     = (int*)(ws + (size_t)HSIZE * 8);
    int*   ohead   = (int*)(ws + (size_t)HSIZE * 8 + (size_t)M * 4);
    int*   slotbuf = (int*)(ws + (size_t)HSIZE * 8 + (size_t)M * 8);
    int*   nxt     = (int*)(ws + (size_t)HSIZE * 8 + (size_t)M * 8 + (size_t)M * SLOTS * 4);

    size_t ff_bytes = (size_t)HSIZE * 8 + (size_t)M * 8;
    hipMemsetAsync(htab, 0xFF, ff_bytes, stream);  // EMPTY_KEY / UINT_MAX / -1 / -1

    const int TB = 256;
    build_hash<<<(M + TB - 1) / TB, TB, 0, stream>>>(
        (const int4*)tgt_coords, M, htab);
    fill_slots<<<(BN + TB - 1) / TB, TB, 0, stream>>>(
        pts_idx, (const int4*)tgt_coords, htab, BN, cnt, slotbuf, ohead, nxt);
    fuse_wave<<<1024, TB, 0, stream>>>(
        pfeat, cnt, (const int4*)slotbuf, ohead, nxt,
        tgt_feats, W_fuse, b_fuse, M, out);
}

// Round 6
// 287.467 us; speedup vs baseline: 3.3569x; 1.1129x over previous
//
#include <hip/hip_runtime.h>

// ---- hash / bucket constants ----
#define HBITS 19
#define HSIZE (1u << HBITS)
#define HMASK (HSIZE - 1u)
#define EMPTY_KEY 0xFFFFFFFFu
#define SLOTS 8   // direct slots per voxel; overflow (P~1e-4) goes to chain

__device__ __forceinline__ unsigned hash_key(unsigned k) {
    return (k * 2654435761u) >> (32 - HBITS);
}

__device__ __forceinline__ unsigned pack_key(int4 c) {
    // c.x = batch (<4), c.y/z/w = xyz in [0,256)
    return ((unsigned)c.x << 24) | ((unsigned)c.y << 16) |
           ((unsigned)c.z << 8) | (unsigned)c.w;
}

// Kernel A: insert voxel keys; htab[h] = (key, min original index).
__global__ __launch_bounds__(256)
void build_hash(const int4* __restrict__ tgt_coords, int M,
                uint2* __restrict__ htab) {
    int v = blockIdx.x * blockDim.x + threadIdx.x;
    if (v >= M) return;
    unsigned key = pack_key(tgt_coords[v]);
    unsigned h = hash_key(key);
    while (true) {
        unsigned prev = atomicCAS(&htab[h].x, EMPTY_KEY, key);
        if (prev == EMPTY_KEY || prev == key) {
            atomicMin(&htab[h].y, (unsigned)v);   // canonical = min index
            break;
        }
        h = (h + 1u) & HMASK;
    }
}

// Kernel B: each point probes the hash for its canonical voxel and claims a
// bucket slot. cnt[] init = -1 (0xFF memset) so atomicAdd+1 gives slot 0,1,...
__global__ __launch_bounds__(256)
void fill_slots(const int* __restrict__ pts_idx,
                const int4* __restrict__ tgt_coords,
                const uint2* __restrict__ htab,
                int BN,
                int* __restrict__ cnt,      // (M) init -1
                int* __restrict__ slotbuf,  // (M*SLOTS) no init needed
                int* __restrict__ ohead,    // (M) init -1
                int* __restrict__ nxt) {    // (BN) no init needed
    int p = blockIdx.x * blockDim.x + threadIdx.x;
    if (p >= BN) return;
    int vox = pts_idx[p];
    unsigned key = pack_key(tgt_coords[vox]);
    unsigned h = hash_key(key);
    uint2 e = htab[h];
    while (e.x != key) { h = (h + 1u) & HMASK; e = htab[h]; }
    int c = (int)e.y;
    int idx = atomicAdd(&cnt[c], 1) + 1;
    if (idx < SLOTS) slotbuf[c * SLOTS + idx] = p;
    else             nxt[p] = atomicExch(&ohead[c], p);   // rare
}

// Kernel C: gather-mean ONLY (round-2's proven VGPR-16 structure).
// Group of 32 lanes per voxel; lane g owns img channels 2g,2g+1.
// All slot row loads independent (overlap); writes mean (M,64) fp32 coalesced.
#define VPB 8
__global__ __launch_bounds__(256)
void gather_mean(const float2* __restrict__ pf2,   // (BN,64) as (BN,32) float2
                 const int* __restrict__ cnt,
                 const int4* __restrict__ slot4,   // slotbuf as (M,2) int4
                 const int* __restrict__ ohead,
                 const int* __restrict__ nxt,
                 int M,
                 float2* __restrict__ mean2) {     // (M,64) as (M,32) float2
    int t = threadIdx.x;
    int grp = t >> 5;
    int g   = t & 31;
    int v = blockIdx.x * VPB + grp;
    if (v >= M) return;

    int n = cnt[v] + 1;
    int4 sa = make_int4(0, 0, 0, 0), sb = make_int4(0, 0, 0, 0);
    if (n > 0) sa = slot4[(size_t)v * 2];
    if (n > 4) sb = slot4[(size_t)v * 2 + 1];
    float2 f0 = {0,0}, f1 = {0,0}, f2 = {0,0}, f3 = {0,0};
    float2 f4 = {0,0}, f5 = {0,0}, f6 = {0,0}, f7 = {0,0};
    if (n > 0) f0 = pf2[(size_t)sa.x * 32 + g];
    if (n > 1) f1 = pf2[(size_t)sa.y * 32 + g];
    if (n > 2) f2 = pf2[(size_t)sa.z * 32 + g];
    if (n > 3) f3 = pf2[(size_t)sa.w * 32 + g];
    if (n > 4) f4 = pf2[(size_t)sb.x * 32 + g];
    if (n > 5) f5 = pf2[(size_t)sb.y * 32 + g];
    if (n > 6) f6 = pf2[(size_t)sb.z * 32 + g];
    if (n > 7) f7 = pf2[(size_t)sb.w * 32 + g];
    float sx = ((f0.x + f1.x) + (f2.x + f3.x)) + ((f4.x + f5.x) + (f6.x + f7.x));
    float sy = ((f0.y + f1.y) + (f2.y + f3.y)) + ((f4.y + f5.y) + (f6.y + f7.y));
    if (n > SLOTS) {   // extremely rare overflow chain
        int p = ohead[v];
        while (p >= 0) {
            float2 f = pf2[(size_t)p * 32 + g];
            sx += f.x; sy += f.y;
            p = nxt[p];
        }
    }
    float inv = 1.0f / fmaxf((float)n, 1.0f);
    mean2[(size_t)v * 32 + g] = make_float2(sx * inv, sy * inv);
}

// Kernel D: ONE THREAD PER VOXEL fp32 GEMV, W via wave-uniform SCALAR loads.
// Lane streams its own x row (tgt 32 + mean 64) as contiguous float4 global
// loads (every fetched byte used), keeps acc[32] in VGPRs, W[k][oc] is
// wave-uniform -> s_load broadcast (no VGPR cost, dual-issues with VALU).
// VALU: 96*32 fmac/voxel = 24 cyc/voxel/CU -> ~8 us at 100% for M=200k.
__global__ __launch_bounds__(256)
void matmul_scalar(const float4* __restrict__ tgt4,   // (M,32) as (M,8) float4
                   const float4* __restrict__ mean4,  // (M,64) as (M,16) float4
                   const float* __restrict__ W,       // (96,32)
                   const float* __restrict__ bias,    // (32,)
                   int M,
                   float4* __restrict__ out4) {       // (M,32) as (M,8) float4
    int v = blockIdx.x * blockDim.x + threadIdx.x;
    if (v >= M) return;

    float acc[32];
#pragma unroll
    for (int oc = 0; oc < 32; ++oc) acc[oc] = bias[oc];

    const float4* xr = tgt4 + (size_t)v * 8;
#pragma unroll 2
    for (int k4 = 0; k4 < 8; ++k4) {
        float4 x = xr[k4];
        const float* w0 = W + k4 * 4 * 32;
#pragma unroll
        for (int oc = 0; oc < 32; ++oc) {
            acc[oc] = fmaf(x.x, w0[oc],      acc[oc]);
            acc[oc] = fmaf(x.y, w0[32 + oc], acc[oc]);
            acc[oc] = fmaf(x.z, w0[64 + oc], acc[oc]);
            acc[oc] = fmaf(x.w, w0[96 + oc], acc[oc]);
        }
    }
    const float4* mr = mean4 + (size_t)v * 16;
#pragma unroll 2
    for (int k4 = 0; k4 < 16; ++k4) {
        float4 x = mr[k4];
        const float* w0 = W + (32 + k4 * 4) * 32;
#pragma unroll
        for (int oc = 0; oc < 32; ++oc) {
            acc[oc] = fmaf(x.x, w0[oc],      acc[oc]);
            acc[oc] = fmaf(x.y, w0[32 + oc], acc[oc]);
            acc[oc] = fmaf(x.z, w0[64 + oc], acc[oc]);
            acc[oc] = fmaf(x.w, w0[96 + oc], acc[oc]);
        }
    }

    float4* o = out4 + (size_t)v * 8;
#pragma unroll
    for (int q = 0; q < 8; ++q)
        o[q] = make_float4(acc[4 * q], acc[4 * q + 1], acc[4 * q + 2], acc[4 * q + 3]);
}

extern "C" void kernel_launch(void* const* d_in, const int* in_sizes, int n_in,
                              void* d_out, int out_size, void* d_ws, size_t ws_size,
                              hipStream_t stream) {
    const float* pfeat      = (const float*)d_in[0];  // (BN,64)
    const float* tgt_feats  = (const float*)d_in[1];  // (M,32)
    const float* W_fuse     = (const float*)d_in[2];  // (96,32)
    const float* b_fuse     = (const float*)d_in[3];  // (32,)
    const int*   tgt_coords = (const int*)d_in[4];    // (M,4)
    const int*   pts_idx    = (const int*)d_in[5];    // (BN,)
    float* out = (float*)d_out;                       // (M,32)

    const int M  = in_sizes[4] / 4;
    const int BN = in_sizes[5];

    // workspace: [htab 4MB | cnt M | ohead M]  <- single 0xFF memset region
    //            [slotbuf M*8 | nxt BN | mean M*64 f32] <- write-before-read
    char* ws = (char*)d_ws;
    uint2* htab    = (uint2*)ws;
    size_t off = (size_t)HSIZE * 8;
    int*   cnt     = (int*)(ws + off);              off += (size_t)M * 4;
    int*   ohead   = (int*)(ws + off);              off += (size_t)M * 4;
    int*   slotbuf = (int*)(ws + off);              off += (size_t)M * SLOTS * 4;
    int*   nxt     = (int*)(ws + off);              off += (size_t)BN * 4;
    float* mean    = (float*)(ws + off);            // M*64 floats

    size_t ff_bytes = (size_t)HSIZE * 8 + (size_t)M * 8;  // htab + cnt + ohead
    hipMemsetAsync(htab, 0xFF, ff_bytes, stream);  // EMPTY_KEY / UINT_MAX / -1 / -1

    const int TB = 256;
    build_hash<<<(M + TB - 1) / TB, TB, 0, stream>>>(
        (const int4*)tgt_coords, M, htab);
    fill_slots<<<(BN + TB - 1) / TB, TB, 0, stream>>>(
        pts_idx, (const int4*)tgt_coords, htab, BN, cnt, slotbuf, ohead, nxt);
    gather_mean<<<(M + VPB - 1) / VPB, TB, 0, stream>>>(
        (const float2*)pfeat, cnt, (const int4*)slotbuf, ohead, nxt, M,
        (float2*)mean);
    matmul_scalar<<<(M + TB - 1) / TB, TB, 0, stream>>>(
        (const float4*)tgt_feats, (const float4*)mean, W_fuse, b_fuse, M,
        (float4*)out);
}